// Round 1
// baseline (225.592 us; speedup 1.0000x reference)
//
#include <hip/hip_runtime.h>
#include <hip/hip_cooperative_groups.h>

namespace cg = cooperative_groups;

// Problem constants from the reference.
#define B_SZ   256
#define V_SZ   128000
#define L_KO   32
#define L_EN   32
#define N_NEG  1024
#define EPS_F  1e-8f
#define MARGIN 2.0f
#define NEG_TH 0.1f

// Single fused cooperative kernel: one block per batch row, 256 threads.
// Phase 1 (all 256 blocks):
//   - all 256 threads: one int4 id load -> 4 negative gathers -> relu sum
//   - wave 0, lanes 0-31 : ko gather -> -log(x+eps)            (masked by ko_len)
//   - wave 0, lanes 32-63: en gather -> -log(x+eps), relu(2-x) (masked by en_len)
//   - block reduce, leader stores per-row partial {self, tgt, mar, neg_sum}
//     into ws[b*4..b*4+3] with agent-scope atomic stores (XCD-coherent).
// grid.sync()
// Phase 2 (block 0 only): 256 threads re-reduce the 256x4 partials and
//   write the 4 scaled outputs. No second launch, no extra launch latency.
__global__ __launch_bounds__(256) void term_loss_fused(
    const float* __restrict__ rep,
    const int*   __restrict__ ko_ids,
    const int*   __restrict__ ko_len,
    const int*   __restrict__ en_ids,
    const int*   __restrict__ en_len,
    const int*   __restrict__ neg_ids,
    float*       __restrict__ ws,     // >= B_SZ*4 floats of workspace
    float*       __restrict__ out)
{
    const int b   = blockIdx.x;
    const int tid = threadIdx.x;
    const float* __restrict__ row = rep + (size_t)b * V_SZ;

    // ---- Phase 1: per-row partials -----------------------------------
    // Negative gathers: 4 consecutive ids per thread via one coalesced
    // int4 load (16 B/lane), then 4 independent gathers (one vmcnt batch).
    const int4 nid = ((const int4*)neg_ids)[tid];
    float s_self = 0.0f, s_tgt = 0.0f, s_mar = 0.0f;
    const float n0 = fmaxf(row[nid.x] - NEG_TH, 0.0f);
    const float n1 = fmaxf(row[nid.y] - NEG_TH, 0.0f);
    const float n2 = fmaxf(row[nid.z] - NEG_TH, 0.0f);
    const float n3 = fmaxf(row[nid.w] - NEG_TH, 0.0f);
    float s_neg = (n0 + n1) + (n2 + n3);

    if (tid < 32) {
        if (tid < ko_len[b]) {
            const float v = row[ko_ids[b * L_KO + tid]];
            s_self = -logf(v + EPS_F);
        }
    } else if (tid < 64) {
        const int l = tid - 32;
        if (l < en_len[b]) {
            const float v = row[en_ids[b * L_EN + l]];
            s_tgt = -logf(v + EPS_F);
            s_mar = fmaxf(MARGIN - v, 0.0f);
        }
    }

    // 64-lane wave reduction.
    #pragma unroll
    for (int off = 32; off > 0; off >>= 1) {
        s_self += __shfl_down(s_self, off, 64);
        s_tgt  += __shfl_down(s_tgt,  off, 64);
        s_mar  += __shfl_down(s_mar,  off, 64);
        s_neg  += __shfl_down(s_neg,  off, 64);
    }

    __shared__ float red[4][4];
    __shared__ float fin[4][4];
    const int wave = tid >> 6;
    const int lane = tid & 63;
    if (lane == 0) {
        red[wave][0] = s_self;
        red[wave][1] = s_tgt;
        red[wave][2] = s_mar;
        red[wave][3] = s_neg;
    }
    __syncthreads();

    if (tid == 0) {
        float a0 = 0.0f, a1 = 0.0f, a2 = 0.0f, a3 = 0.0f;
        #pragma unroll
        for (int w = 0; w < 4; ++w) {
            a0 += red[w][0];
            a1 += red[w][1];
            a2 += red[w][2];
            a3 += red[w][3];
        }
        const int kl = ko_len[b];
        const int el = en_len[b];
        const float p0 = (kl > 0) ? (a0 / (float)kl) : 0.0f; // row self mean
        const float p1 = (el > 0) ? (a1 / (float)el) : 0.0f; // row target mean
        const float p2 = (el > 0) ? (a2 / (float)el) : 0.0f; // row margin mean
        // Agent-scope atomic stores: coherent across XCDs via the LLC.
        __hip_atomic_store(&ws[b * 4 + 0], p0, __ATOMIC_RELAXED, __HIP_MEMORY_SCOPE_AGENT);
        __hip_atomic_store(&ws[b * 4 + 1], p1, __ATOMIC_RELAXED, __HIP_MEMORY_SCOPE_AGENT);
        __hip_atomic_store(&ws[b * 4 + 2], p2, __ATOMIC_RELAXED, __HIP_MEMORY_SCOPE_AGENT);
        __hip_atomic_store(&ws[b * 4 + 3], a3, __ATOMIC_RELAXED, __HIP_MEMORY_SCOPE_AGENT);
    }

    // ---- Grid-wide barrier -------------------------------------------
    cg::this_grid().sync();

    // ---- Phase 2: final reduce by block 0 ----------------------------
    if (b == 0) {
        const int c  = tid & 3;   // component 0..3
        const int r0 = tid >> 2;  // base row 0..63
        float v = 0.0f;
        #pragma unroll
        for (int k = 0; k < 4; ++k) {
            v += __hip_atomic_load(&ws[(size_t)(r0 + 64 * k) * 4 + c],
                                   __ATOMIC_RELAXED, __HIP_MEMORY_SCOPE_AGENT);
        }
        // Sum lanes with equal (lane & 3) within the wave.
        #pragma unroll
        for (int off = 32; off >= 4; off >>= 1)
            v += __shfl_down(v, off, 64);
        if (lane < 4) fin[wave][lane] = v;   // lane<4 => c == lane
        __syncthreads();
        if (tid < 4) {
            const float a = fin[0][tid] + fin[1][tid] + fin[2][tid] + fin[3][tid];
            const float scale = (tid == 3)
                ? (1.0f / ((float)B_SZ * (float)N_NEG))
                : (1.0f / (float)B_SZ);
            out[tid] = a * scale;
        }
    }
}

extern "C" void kernel_launch(void* const* d_in, const int* in_sizes, int n_in,
                              void* d_out, int out_size, void* d_ws, size_t ws_size,
                              hipStream_t stream)
{
    const float* rep     = (const float*)d_in[0];
    const int*   ko_ids  = (const int*)  d_in[1];
    const int*   ko_len  = (const int*)  d_in[2];
    const int*   en_ids  = (const int*)  d_in[3];
    const int*   en_len  = (const int*)  d_in[4];
    const int*   neg_ids = (const int*)  d_in[5];
    float*       out     = (float*)d_out;
    float*       ws      = (float*)d_ws;   // 256*4 floats = 4 KB used

    void* args[] = {
        (void*)&rep, (void*)&ko_ids, (void*)&ko_len,
        (void*)&en_ids, (void*)&en_len, (void*)&neg_ids,
        (void*)&ws, (void*)&out
    };
    hipLaunchCooperativeKernel((const void*)term_loss_fused,
                               dim3(B_SZ), dim3(256), args, 0, stream);
}

// Round 2
// 177.745 us; speedup vs baseline: 1.2692x; 1.2692x over previous
//
#include <hip/hip_runtime.h>

// Problem constants from the reference.
#define B_SZ   256
#define V_SZ   128000
#define L_KO   32
#define L_EN   32
#define N_NEG  1024
#define EPS_F  1e-8f
#define MARGIN 2.0f
#define NEG_TH 0.1f

// Kernel 1: one block per batch row, 1024 threads = 16 waves (4 waves/SIMD).
//  - all 1024 threads   : 1 coalesced id load + 1 negative gather + relu
//  - wave 0, lanes 0-31 : ko gather -> -log(x+eps)            (masked by ko_len)
//  - wave 0, lanes 32-63: en gather -> -log(x+eps), relu(2-x) (masked by en_len)
// 16 waves/CU (vs 4 before) quadruples resident-wave MLP for the random
// gathers, which are all misses to distinct 128B lines (L3 is evicted every
// iteration by the harness's 500 MiB re-poison fills).
// Writes per-row partials {self_mean, tgt_mean, margin_mean, neg_sum} as
// float4 into partials[b]. No atomics, no d_out zeroing needed.
__global__ __launch_bounds__(1024) void term_loss_partial(
    const float* __restrict__ rep,
    const int*   __restrict__ ko_ids,
    const int*   __restrict__ ko_len,
    const int*   __restrict__ en_ids,
    const int*   __restrict__ en_len,
    const int*   __restrict__ neg_ids,
    float4*      __restrict__ partials)
{
    const int b   = blockIdx.x;
    const int tid = threadIdx.x;
    const float* __restrict__ row = rep + (size_t)b * V_SZ;

    // Hoist the (scalar, L2-resident) length loads so they overlap the gather.
    const int kl = ko_len[b];
    const int el = en_len[b];

    // One negative gather per thread: coalesced 4B id load, then the gather.
    const int   nid = neg_ids[tid];
    float s_self = 0.0f, s_tgt = 0.0f, s_mar = 0.0f;
    const float nv  = row[nid];
    float s_neg = fmaxf(nv - NEG_TH, 0.0f);

    if (tid < 32) {
        if (tid < kl) {
            const float v = row[ko_ids[b * L_KO + tid]];
            s_self = -logf(v + EPS_F);
        }
    } else if (tid < 64) {
        const int l = tid - 32;
        if (l < el) {
            const float v = row[en_ids[b * L_EN + l]];
            s_tgt = -logf(v + EPS_F);
            s_mar = fmaxf(MARGIN - v, 0.0f);
        }
    }

    // 64-lane wave reduction.
    #pragma unroll
    for (int off = 32; off > 0; off >>= 1) {
        s_self += __shfl_down(s_self, off, 64);
        s_tgt  += __shfl_down(s_tgt,  off, 64);
        s_mar  += __shfl_down(s_mar,  off, 64);
        s_neg  += __shfl_down(s_neg,  off, 64);
    }

    __shared__ float red[16][4];
    const int wave = tid >> 6;
    if ((tid & 63) == 0) {
        red[wave][0] = s_self;
        red[wave][1] = s_tgt;
        red[wave][2] = s_mar;
        red[wave][3] = s_neg;
    }
    __syncthreads();

    if (tid == 0) {
        float a0 = 0.0f, a1 = 0.0f, a2 = 0.0f, a3 = 0.0f;
        #pragma unroll
        for (int w = 0; w < 16; ++w) {
            a0 += red[w][0];
            a1 += red[w][1];
            a2 += red[w][2];
            a3 += red[w][3];
        }
        float4 p;
        p.x = (kl > 0) ? (a0 / (float)kl) : 0.0f;   // per-row self mean
        p.y = (el > 0) ? (a1 / (float)el) : 0.0f;   // per-row target mean
        p.z = (el > 0) ? (a2 / (float)el) : 0.0f;   // per-row margin mean
        p.w = a3;                                   // per-row negative sum
        partials[b] = p;
    }
}

// Kernel 2: single block, 256 threads. Thread t loads partials[t] (float4),
// block-reduces each component, thread 0 writes the 4 scaled outputs.
__global__ __launch_bounds__(256) void term_loss_reduce(
    const float4* __restrict__ partials,
    float*        __restrict__ out)
{
    const int tid = threadIdx.x;
    float4 p = partials[tid];

    #pragma unroll
    for (int off = 32; off > 0; off >>= 1) {
        p.x += __shfl_down(p.x, off, 64);
        p.y += __shfl_down(p.y, off, 64);
        p.z += __shfl_down(p.z, off, 64);
        p.w += __shfl_down(p.w, off, 64);
    }

    __shared__ float4 red[4];
    const int wave = tid >> 6;
    if ((tid & 63) == 0) red[wave] = p;
    __syncthreads();

    if (tid == 0) {
        float4 a = red[0];
        #pragma unroll
        for (int w = 1; w < 4; ++w) {
            a.x += red[w].x;
            a.y += red[w].y;
            a.z += red[w].z;
            a.w += red[w].w;
        }
        out[0] = a.x * (1.0f / (float)B_SZ);
        out[1] = a.y * (1.0f / (float)B_SZ);
        out[2] = a.z * (1.0f / (float)B_SZ);
        out[3] = a.w * (1.0f / ((float)B_SZ * (float)N_NEG));
    }
}

extern "C" void kernel_launch(void* const* d_in, const int* in_sizes, int n_in,
                              void* d_out, int out_size, void* d_ws, size_t ws_size,
                              hipStream_t stream)
{
    const float* rep     = (const float*)d_in[0];
    const int*   ko_ids  = (const int*)  d_in[1];
    const int*   ko_len  = (const int*)  d_in[2];
    const int*   en_ids  = (const int*)  d_in[3];
    const int*   en_len  = (const int*)  d_in[4];
    const int*   neg_ids = (const int*)  d_in[5];
    float*       out     = (float*)d_out;
    float4*      part    = (float4*)d_ws;   // 256 * 16 B = 4 KB scratch

    term_loss_partial<<<B_SZ, 1024, 0, stream>>>(
        rep, ko_ids, ko_len, en_ids, en_len, neg_ids, part);
    term_loss_reduce<<<1, 256, 0, stream>>>(part, out);
}